// Round 4
// baseline (680.841 us; speedup 1.0000x reference)
//
#include <hip/hip_runtime.h>

// B=256, C=2048, K=18, HW=24*8=192, all fp32.
// out[b, 0:C]  = pool_global_feat[b,:]
// out[b, C:2C] = max_k( sum_hw masks[b,k,hw]*feat[b,c,hw] ) / HW
#define BB 256
#define CC 2048
#define KK 18
#define HWW 192
#define CT 64                 // channels per block tile
#define QQ 4                  // hw quarters = waves per block
#define QLEN (HWW / QQ)       // 48 floats per quarter
#define PADROW 196            // 192 + 4-float pad: lane bank stride 4 -> conflict-free b128
#define BLOCK (CT * QQ)       // 256

__global__ __launch_bounds__(BLOCK)
void pgfa_pose_guided_kernel(const float* __restrict__ feat,
                             const float* __restrict__ masks,
                             const float* __restrict__ pgf,
                             float* __restrict__ out) {
    // 64 * 196 * 4 = 50176 B; reused for the q-partial reduction afterwards.
    // __align__(16): float4 LDS access requires 16-B alignment, which a plain
    // float[] does NOT guarantee.
    __shared__ __align__(16) float lds[CT * PADROW];

    const int tid = threadIdx.x;
    const int b   = blockIdx.y;
    const int c0  = blockIdx.x * CT;

    // ---- Stage feat tile [CT][HWW] -> LDS (padded rows) ----
    // 64*48 = 3072 float4s / 256 threads = 12 per thread, fully coalesced.
    {
        const float4* g4 = (const float4*)(feat + ((size_t)b * CC + c0) * HWW);
        float4 tmp[12];
        #pragma unroll
        for (int n = 0; n < 12; ++n)
            tmp[n] = g4[tid + n * BLOCK];
        #pragma unroll
        for (int n = 0; n < 12; ++n) {
            int i  = tid + n * BLOCK;
            int c  = i / (HWW / 4);
            int h4 = i % (HWW / 4);
            *(float4*)(&lds[c * PADROW + h4 * 4]) = tmp[n];
        }
    }
    __syncthreads();

    const int c = tid & (CT - 1);
    const int q = tid >> 6;          // uniform per wave; plain loads (masks are L1-resident)

    const float* mq   = masks + (size_t)b * KK * HWW + q * QLEN;
    const float* frow = &lds[c * PADROW + q * QLEN];

    float acc[KK];
    #pragma unroll
    for (int k = 0; k < KK; ++k) acc[k] = 0.0f;

    #pragma unroll 2
    for (int j = 0; j < QLEN / 4; ++j) {
        const float4 f = *(const float4*)(frow + j * 4);   // ds_read_b128, conflict-free
        #pragma unroll
        for (int k = 0; k < KK; ++k) {
            const float4 m = *(const float4*)(mq + k * HWW + j * 4);  // wave-uniform address
            acc[k] += m.x * f.x;
            acc[k] += m.y * f.y;
            acc[k] += m.z * f.z;
            acc[k] += m.w * f.w;
        }
    }

    __syncthreads();   // everyone done reading the feat tile; reuse LDS
    // partial[c][k][q] : c*72 + k*4 + q   (max idx 4607 < 12544 floats)
    float* part = lds;
    #pragma unroll
    for (int k = 0; k < KK; ++k)
        part[c * (KK * QQ) + k * QQ + q] = acc[k];
    __syncthreads();

    if (tid < CT) {
        float vmax = -INFINITY;
        #pragma unroll
        for (int k = 0; k < KK; ++k) {
            // 16-B aligned: tid*288 B + k*16 B
            const float4 p = *(const float4*)(&part[tid * (KK * QQ) + k * QQ]);
            const float s = (p.x + p.y) + (p.z + p.w);
            vmax = fmaxf(vmax, s);
        }
        float* orow = out + (size_t)b * (2 * CC);
        orow[c0 + tid]      = pgf[(size_t)b * CC + c0 + tid];
        orow[CC + c0 + tid] = vmax * (1.0f / (float)HWW);
    }
}

extern "C" void kernel_launch(void* const* d_in, const int* in_sizes, int n_in,
                              void* d_out, int out_size, void* d_ws, size_t ws_size,
                              hipStream_t stream) {
    const float* feat  = (const float*)d_in[0];  // [B, C, H, W] fp32
    const float* masks = (const float*)d_in[1];  // [B, K, H, W] fp32
    const float* pgf   = (const float*)d_in[2];  // [B, C] fp32
    float* out = (float*)d_out;                  // [B, 2C] fp32

    dim3 grid(CC / CT, BB);   // (32, 256) = 8192 blocks
    pgfa_pose_guided_kernel<<<grid, BLOCK, 0, stream>>>(feat, masks, pgf, out);
}